// Round 15
// baseline (223.839 us; speedup 1.0000x reference)
//
#include <hip/hip_runtime.h>

#define B_SZ 2
#define T_SZ 4096

typedef unsigned short u16;
typedef __attribute__((ext_vector_type(8))) short short8;
typedef __attribute__((ext_vector_type(4))) float f32x4;
typedef __attribute__((ext_vector_type(4))) unsigned short u16x4;

#define CEXP 0.51006973f   // (8^-0.5) * log2(e), folded into Q projection

__device__ __forceinline__ u16 f2bf(float f) {            // round-to-nearest-even
    unsigned int u;
    __builtin_memcpy(&u, &f, 4);
    u = (u + 0x7fffu + ((u >> 16) & 1u)) >> 16;
    return (u16)u;
}
__device__ __forceinline__ unsigned int rbits(float f) {  // bits + half-up round offset
    unsigned int u;
    __builtin_memcpy(&u, &f, 4);
    return u + 0x8000u;
}
__device__ __forceinline__ f32x4 mfma16(short8 a, short8 b, f32x4 c) {
    return __builtin_amdgcn_mfma_f32_16x16x32_bf16(a, b, c, 0, 0, 0);
}

// ---------- prep: x/cond -> bf16 convert + LDS-tiled weight transposes ----------
// Transpose via 64x64 LDS tile: coalesced float4 reads, u16x4 row writes.
// (Old scalar stride-512 stores touched ~1.5M cache lines = ~98MB effective traffic.)
__global__ void k_prep(const float* __restrict__ x, const float* __restrict__ cond,
                       const float* __restrict__ Wqk, const float* __restrict__ Wv,
                       const float* __restrict__ Wu, u16* __restrict__ xb, u16* __restrict__ cb,
                       u16* __restrict__ Wqk_t, u16* __restrict__ Wv_t, u16* __restrict__ Wu_t) {
    int blk = blockIdx.x, tid = threadIdx.x;
    if (blk < 8192) {                                     // x / cond convert, 4 elems/thread
        const float* s = blk < 4096 ? x : cond;
        u16* d = blk < 4096 ? xb : cb;
        int i = ((blk & 4095) * 256 + tid) * 4;
        float4 v = *(const float4*)(s + i);
        u16x4 o = { f2bf(v.x), f2bf(v.y), f2bf(v.z), f2bf(v.w) };
        *(u16x4*)(d + i) = o;
        return;
    }
    __shared__ u16 T[64][72];
    const float* src; u16* dst; int N, ti;
    if (blk < 8320)      { src = Wqk; dst = Wqk_t; N = 1024; ti = blk - 8192; }
    else if (blk < 8384) { src = Wv;  dst = Wv_t;  N = 512;  ti = blk - 8320; }
    else                 { src = Wu;  dst = Wu_t;  N = 512;  ti = blk - 8384; }
    int nt = N >> 6;
    int bi = ti / nt, bj = ti - bi * nt;                  // k-tile, n-tile
    int kb = bi * 64, nb = bj * 64;
    int r = tid >> 2, c4 = (tid & 3) * 16;
#pragma unroll
    for (int jj = 0; jj < 4; ++jj) {                      // coalesced read: row kb+r
        float4 v = *(const float4*)(src + (size_t)(kb + r) * N + nb + c4 + jj * 4);
        u16x4 w = { f2bf(v.x), f2bf(v.y), f2bf(v.z), f2bf(v.w) };
        *(u16x4*)(&T[r][c4 + jj * 4]) = w;
    }
    __syncthreads();
#pragma unroll
    for (int jj = 0; jj < 4; ++jj) {                      // write row nb+r of dst (u16x4)
        int c = c4 + jj * 4;
        u16x4 w = { T[c][r], T[c + 1][r], T[c + 2][r], T[c + 3][r] };
        *(u16x4*)(dst + (size_t)(nb + r) * 512 + kb + c) = w;
    }
}

// ---------- LDS-tiled bf16 GEMM, DEPTH-4 register pipeline ----------
// TM x TN tile, 4 waves, BK=32, K=512 = 16 slices = 4x4 (outer runtime x inner
// unrolled stage d). Slice s is prefetched at s-4 (~900+ cyc ahead) -> the
// vmcnt wait at the LDS-write is fully covered (was ~600 cyc exposed/iter).
// MODE 0 (out): A=Wu_t (cho as M), B=at -> out[t][512] float4 + bias.
// MODE 1 (qk):  A=Wqk_t (ch as M), B=cb -> Qh[b,h,t,64]*CEXP / Kh, u16x4.
// MODE 2 (v):   A=xb (tok as M),   B=Wv_t -> Vb[b,h,kt,64d,64k], u16x4 along k64.
template <typename OutT, int MODE, int TM, int TN>
__global__ __launch_bounds__(256) void k_gemm5(const u16* __restrict__ A, const u16* __restrict__ Bt,
                                               const float* __restrict__ bias, OutT* __restrict__ C,
                                               OutT* __restrict__ C2) {
    const int K = 512;
    constexpr int MI = TM / 32, NJ = TN / 32;
    constexpr int NA = TM / 64, NB = TN / 64;
    int m0 = blockIdx.x * TM, n0 = blockIdx.y * TN;
    int tid = threadIdx.x;
    int wave = tid >> 6, lane = tid & 63, l16 = lane & 15, q = lane >> 4;
    int mo = (wave & 1) * (TM / 2), no = (wave >> 1) * (TN / 2);

    __shared__ __align__(16) u16 As[TM * 72];
    __shared__ __align__(16) u16 Bs[TN * 72];

    f32x4 acc[MI][NJ];
#pragma unroll
    for (int i = 0; i < MI; ++i)
#pragma unroll
        for (int j = 0; j < NJ; ++j) acc[i][j] = (f32x4){0.f, 0.f, 0.f, 0.f};

    const u16* ap[NA]; const u16* bp[NB];
    short8 ra[4][NA], rb[4][NB];
#pragma unroll
    for (int jj = 0; jj < NA; ++jj) {
        int id = tid + 256 * jj;
        ap[jj] = A + (size_t)(m0 + (id >> 2)) * K + (id & 3) * 8;
    }
#pragma unroll
    for (int jj = 0; jj < NB; ++jj) {
        int id = tid + 256 * jj;
        bp[jj] = Bt + (size_t)(n0 + (id >> 2)) * K + (id & 3) * 8;
    }
#pragma unroll
    for (int d = 0; d < 4; ++d) {                         // prologue: slices 0..3
#pragma unroll
        for (int jj = 0; jj < NA; ++jj) ra[d][jj] = *(const short8*)(ap[jj] + d * 32);
#pragma unroll
        for (int jj = 0; jj < NB; ++jj) rb[d][jj] = *(const short8*)(bp[jj] + d * 32);
    }

#pragma unroll 1
    for (int ko = 0; ko < 4; ++ko) {
#pragma unroll
        for (int d = 0; d < 4; ++d) {                     // slice = ko*4+d
            __syncthreads();
#pragma unroll
            for (int jj = 0; jj < NA; ++jj) {
                int id = tid + 256 * jj;
                *(short8*)(&As[(id >> 2) * 72 + (id & 3) * 8]) = ra[d][jj];
            }
#pragma unroll
            for (int jj = 0; jj < NB; ++jj) {
                int id = tid + 256 * jj;
                *(short8*)(&Bs[(id >> 2) * 72 + (id & 3) * 8]) = rb[d][jj];
            }
            __syncthreads();

            int s4 = ko * 4 + d + 4;                      // prefetch slice s+4
            if (s4 > 15) s4 = 15;                         // tail: harmless reload, never consumed
#pragma unroll
            for (int jj = 0; jj < NA; ++jj) ra[d][jj] = *(const short8*)(ap[jj] + s4 * 32);
#pragma unroll
            for (int jj = 0; jj < NB; ++jj) rb[d][jj] = *(const short8*)(bp[jj] + s4 * 32);
            __builtin_amdgcn_sched_barrier(0);

            short8 af[MI], bf[NJ];
#pragma unroll
            for (int i = 0; i < MI; ++i) af[i] = *(const short8*)(&As[(mo + i * 16 + l16) * 72 + q * 8]);
#pragma unroll
            for (int j = 0; j < NJ; ++j) bf[j] = *(const short8*)(&Bs[(no + j * 16 + l16) * 72 + q * 8]);
#pragma unroll
            for (int i = 0; i < MI; ++i)
#pragma unroll
                for (int j = 0; j < NJ; ++j) acc[i][j] = mfma16(af[i], bf[j], acc[i][j]);
        }
    }

    // epilogue: Mrow = m0+mo+i*16+q*4+r (r consecutive), Ncol = n0+no+j*16+l16
#pragma unroll
    for (int i = 0; i < MI; ++i) {
        int mb = m0 + mo + i * 16 + q * 4;
#pragma unroll
        for (int j = 0; j < NJ; ++j) {
            int nc = n0 + no + j * 16 + l16;
            if constexpr (MODE == 0) {                         // out: M=cho, N=token
                float4 bb = *(const float4*)(bias + mb);
                float4 w = { acc[i][j][0] + bb.x, acc[i][j][1] + bb.y,
                             acc[i][j][2] + bb.z, acc[i][j][3] + bb.w };
                *(float4*)(&C[(size_t)nc * 512 + mb]) = w;
            } else if constexpr (MODE == 1) {                  // qk: M=ch, N=token
                int b = nc >> 12, t = nc & 4095;
                int h = (mb & 511) >> 6, d = mb & 63;
                size_t addr = ((size_t)((b * 8 + h) * 4096 + t)) * 64 + d;
                if (mb < 512) {
                    u16x4 w = { f2bf(acc[i][j][0] * CEXP), f2bf(acc[i][j][1] * CEXP),
                                f2bf(acc[i][j][2] * CEXP), f2bf(acc[i][j][3] * CEXP) };
                    *(u16x4*)(&C[addr]) = w;
                } else {
                    u16x4 w = { f2bf(acc[i][j][0]), f2bf(acc[i][j][1]),
                                f2bf(acc[i][j][2]), f2bf(acc[i][j][3]) };
                    *(u16x4*)(&C2[addr]) = w;
                }
            } else {                                           // v: M=token, N=ch
                int b = mb >> 12, t = mb & 4095;
                int kt = t >> 6, k64 = t & 63;
                int h = nc >> 6, d = nc & 63;
                size_t addr = ((((size_t)(b * 8 + h) * 64 + kt) * 64 + d) << 6) + k64;
                u16x4 w = { f2bf(acc[i][j][0]), f2bf(acc[i][j][1]),
                            f2bf(acc[i][j][2]), f2bf(acc[i][j][3]) };
                *(u16x4*)(&C[addr]) = w;
            }
        }
    }
}

// ---------- flash: 8-wave in-block split-K (UNCHANGED from r14: validated 94.7us) ----------
__global__ __launch_bounds__(512) void k_flash(const u16* __restrict__ Qh, const u16* __restrict__ Kh,
                                               const u16* __restrict__ Vb, u16* __restrict__ o) {
    int bid = blockIdx.x;
    int h = bid & 7, qt = (bid >> 3) & 31, b = bid >> 8;
    int tid = threadIdx.x;
    int wave = tid >> 6, lane = tid & 63, l16 = lane & 15, q = lane >> 4;
    int ks = wave >> 2, w4 = wave & 3;
    int t256 = tid & 255;

    __shared__ __align__(16) u16 smem[2 * (64 * 80 + 64 * 72)];   // 38912 B
    u16* Kt = smem + ks * (64 * 80 + 64 * 72);                    // [key][d], 160B rows
    u16* Vt = Kt + 64 * 80;                                       // [d][key], 144B rows

    int head = b * 8 + h;
    short8 qf[2][2];
#pragma unroll
    for (int g = 0; g < 2; ++g) {
        const u16* qp = Qh + ((size_t)head * 4096 + qt * 128 + g * 64 + w4 * 16 + l16) * 64 + q * 8;
        qf[g][0] = *(const short8*)(qp);
        qf[g][1] = *(const short8*)(qp + 32);
    }

    const u16* kb = Kh + (size_t)head * 4096 * 64;
    const u16* vb = Vb + (size_t)head * 4096 * 64;

    int r0 = t256 >> 3, g0 = t256 & 7;
    u16* kw0 = &Kt[r0 * 80 + g0 * 8];
    u16* kw1 = &Kt[(r0 + 32) * 80 + g0 * 8];
    u16* vw0 = &Vt[r0 * 72 + g0 * 8];
    u16* vw1 = &Vt[(r0 + 32) * 72 + g0 * 8];

    f32x4 oacc[2][4];
#pragma unroll
    for (int g = 0; g < 2; ++g)
#pragma unroll
        for (int c = 0; c < 4; ++c) oacc[g][c] = (f32x4){0.f, 0.f, 0.f, 0.f};
    f32x4 lacc[2];
    lacc[0] = (f32x4){0.f, 0.f, 0.f, 0.f};
    lacc[1] = (f32x4){0.f, 0.f, 0.f, 0.f};
    const short8 ones = { 0x3F80, 0x3F80, 0x3F80, 0x3F80, 0x3F80, 0x3F80, 0x3F80, 0x3F80 };
    int pi0 = (l16 >> 2) * 8 + (l16 & 3);

    size_t off0 = (size_t)(ks * 32 + (qt & 31)) * 4096;
    short8 rk0 = *(const short8*)(kb + off0 + t256 * 8);
    short8 rk1 = *(const short8*)(kb + off0 + t256 * 8 + 2048);
    short8 rv0 = *(const short8*)(vb + off0 + t256 * 8);
    short8 rv1 = *(const short8*)(vb + off0 + t256 * 8 + 2048);

#pragma unroll 1
    for (int it = 0; it < 32; ++it) {
        __syncthreads();
        *(short8*)kw0 = rk0;
        *(short8*)kw1 = rk1;
        *(short8*)vw0 = rv0;
        *(short8*)vw1 = rv1;
        __syncthreads();

        size_t offn = (size_t)(ks * 32 + ((qt + it + 1) & 31)) * 4096;  // last iter: harmless reload
        rk0 = *(const short8*)(kb + offn + t256 * 8);
        rk1 = *(const short8*)(kb + offn + t256 * 8 + 2048);
        rv0 = *(const short8*)(vb + offn + t256 * 8);
        rv1 = *(const short8*)(vb + offn + t256 * 8 + 2048);
        __builtin_amdgcn_sched_barrier(0);

#pragma unroll
        for (int kk = 0; kk < 2; ++kk) {
            const u16* ka = &Kt[(kk * 32 + pi0) * 80 + q * 8];
            short8 A00 = *(const short8*)(ka);
            short8 A01 = *(const short8*)(ka + 32);
            short8 A10 = *(const short8*)(ka + 4 * 80);
            short8 A11 = *(const short8*)(ka + 4 * 80 + 32);
            short8 vfc[4];
#pragma unroll
            for (int c = 0; c < 4; ++c)
                vfc[c] = *(const short8*)(&Vt[(c * 16 + l16) * 72 + kk * 32 + q * 8]);

#pragma unroll
            for (int g = 0; g < 2; ++g) {
                f32x4 s0 = (f32x4){0.f, 0.f, 0.f, 0.f};
                f32x4 s1 = (f32x4){0.f, 0.f, 0.f, 0.f};
                s0 = mfma16(A00, qf[g][0], s0); s0 = mfma16(A01, qf[g][1], s0);
                s1 = mfma16(A10, qf[g][0], s1); s1 = mfma16(A11, qf[g][1], s1);

                uint4 pd;
                pd.x = __builtin_amdgcn_perm(rbits(__builtin_amdgcn_exp2f(s0[1])),
                                             rbits(__builtin_amdgcn_exp2f(s0[0])), 0x07060302u);
                pd.y = __builtin_amdgcn_perm(rbits(__builtin_amdgcn_exp2f(s0[3])),
                                             rbits(__builtin_amdgcn_exp2f(s0[2])), 0x07060302u);
                pd.z = __builtin_amdgcn_perm(rbits(__builtin_amdgcn_exp2f(s1[1])),
                                             rbits(__builtin_amdgcn_exp2f(s1[0])), 0x07060302u);
                pd.w = __builtin_amdgcn_perm(rbits(__builtin_amdgcn_exp2f(s1[3])),
                                             rbits(__builtin_amdgcn_exp2f(s1[2])), 0x07060302u);
                short8 pf;
                __builtin_memcpy(&pf, &pd, 16);

                lacc[g] = mfma16(ones, pf, lacc[g]);
#pragma unroll
                for (int c = 0; c < 4; ++c)
                    oacc[g][c] = mfma16(vfc[c], pf, oacc[g][c]);
            }
        }
    }

    // ---- combine split-K partners (additive: shared implicit exp base) ----
    __syncthreads();
    float* red = (float*)smem;
    if (ks == 1) {
        float* rp = red + ((w4 * 64 + lane) * 37);
#pragma unroll
        for (int g = 0; g < 2; ++g)
#pragma unroll
            for (int c = 0; c < 4; ++c)
#pragma unroll
                for (int r = 0; r < 4; ++r) rp[g * 16 + c * 4 + r] = oacc[g][c][r];
        rp[32] = lacc[0][0];
        rp[33] = lacc[1][0];
    }
    __syncthreads();
    if (ks == 0) {
        const float* rp = red + ((w4 * 64 + lane) * 37);
#pragma unroll
        for (int g = 0; g < 2; ++g) {
#pragma unroll
            for (int c = 0; c < 4; ++c)
#pragma unroll
                for (int r = 0; r < 4; ++r) oacc[g][c][r] += rp[g * 16 + c * 4 + r];
            float inv = 1.f / (lacc[g][0] + rp[32 + g]);
            u16* ob = o + (size_t)(b * T_SZ + qt * 128 + g * 64 + w4 * 16 + l16) * 512 + h * 64 + q * 4;
#pragma unroll
            for (int c = 0; c < 4; ++c) {
                u16x4 w = { f2bf(oacc[g][c][0] * inv), f2bf(oacc[g][c][1] * inv),
                            f2bf(oacc[g][c][2] * inv), f2bf(oacc[g][c][3] * inv) };
                *(u16x4*)(ob + c * 16) = w;
            }
        }
    }
}

extern "C" void kernel_launch(void* const* d_in, const int* in_sizes, int n_in,
                              void* d_out, int out_size, void* d_ws, size_t ws_size,
                              hipStream_t stream) {
    const float* x    = (const float*)d_in[0];   // [2,4096,512] f32
    const float* cond = (const float*)d_in[1];   // [2,4096,512] f32
    const float* Wqk  = (const float*)d_in[2];   // [512,1024]   f32
    const float* Wv   = (const float*)d_in[3];   // [512,512]    f32
    const float* Wu   = (const float*)d_in[4];   // [512,512]    f32
    const float* bu   = (const float*)d_in[5];   // [512]        f32
    float* out = (float*)d_out;                  // [2,4096,512] f32

    const size_t MT = (size_t)B_SZ * T_SZ;       // 8192
    u16* xb    = (u16*)d_ws;                     // [8192,512]          8 MB
    u16* cb    = xb + MT * 512;                  // [8192,512]          8 MB
    u16* qh_ws = cb + MT * 512;                  // [16 heads,4096,64]  8 MB (Q pre-scaled)
    u16* kh_ws = qh_ws + MT * 512;               // [16 heads,4096,64]  8 MB
    u16* vb_ws = kh_ws + MT * 512;               // [16,64kt,64d,64k]   8 MB
    u16* at_ws = vb_ws + MT * 512;               // [8192,512]          8 MB
    u16* Wqk_t = at_ws + MT * 512;               // [1024,512]          1 MB
    u16* Wv_t  = Wqk_t + (size_t)1024 * 512;     // [512,512]         0.5 MB
    u16* Wu_t  = Wv_t + (size_t)512 * 512;       // [512,512]         0.5 MB

    k_prep<<<8448, 256, 0, stream>>>(x, cond, Wqk, Wv, Wu, xb, cb, Wqk_t, Wv_t, Wu_t);

    // qk proj: A=Wqk_t (1024 ch), B=cb. grid (8,128)=1024 blocks = 4/CU.
    k_gemm5<u16, 1, 128, 64><<<dim3(8, 128), 256, 0, stream>>>(Wqk_t, cb, nullptr, qh_ws, kh_ws);
    // v proj: A=xb (tokens), B=Wv_t. grid (128,8)=1024 blocks = 4/CU.
    k_gemm5<u16, 2, 64, 64><<<dim3(128, 8), 256, 0, stream>>>(xb, Wv_t, nullptr, vb_ws, nullptr);
    k_flash<<<512, 512, 0, stream>>>(qh_ws, kh_ws, vb_ws, at_ws);
    // out proj: A=Wu_t (cho), B=at, +bias. grid (8,128)=1024 blocks = 4/CU.
    k_gemm5<float, 0, 64, 64><<<dim3(8, 128), 256, 0, stream>>>(Wu_t, at_ws, bu, out, nullptr);
}

// Round 16
// 212.793 us; speedup vs baseline: 1.0519x; 1.0519x over previous
//
#include <hip/hip_runtime.h>

#define B_SZ 2
#define T_SZ 4096

typedef unsigned short u16;
typedef __attribute__((ext_vector_type(8))) short short8;
typedef __attribute__((ext_vector_type(4))) float f32x4;
typedef __attribute__((ext_vector_type(4))) unsigned short u16x4;

#define CEXP 0.51006973f   // (8^-0.5) * log2(e), folded into Q projection

__device__ __forceinline__ u16 f2bf(float f) {            // round-to-nearest-even
    unsigned int u;
    __builtin_memcpy(&u, &f, 4);
    u = (u + 0x7fffu + ((u >> 16) & 1u)) >> 16;
    return (u16)u;
}
__device__ __forceinline__ unsigned int rbits(float f) {  // bits + half-up round offset
    unsigned int u;
    __builtin_memcpy(&u, &f, 4);
    return u + 0x8000u;
}
__device__ __forceinline__ f32x4 mfma16(short8 a, short8 b, f32x4 c) {
    return __builtin_amdgcn_mfma_f32_16x16x32_bf16(a, b, c, 0, 0, 0);
}

// ---------- prep: LDS-tiled weight transposes ONLY (activations convert in-GEMM) ----------
__global__ void k_prep(const float* __restrict__ Wqk, const float* __restrict__ Wv,
                       const float* __restrict__ Wu, u16* __restrict__ Wqk_t,
                       u16* __restrict__ Wv_t, u16* __restrict__ Wu_t) {
    int blk = blockIdx.x, tid = threadIdx.x;
    __shared__ u16 T[64][72];
    const float* src; u16* dst; int N, ti;
    if (blk < 128)      { src = Wqk; dst = Wqk_t; N = 1024; ti = blk; }
    else if (blk < 192) { src = Wv;  dst = Wv_t;  N = 512;  ti = blk - 128; }
    else                { src = Wu;  dst = Wu_t;  N = 512;  ti = blk - 192; }
    int nt = N >> 6;
    int bi = ti / nt, bj = ti - bi * nt;
    int kb = bi * 64, nb = bj * 64;
    int r = tid >> 2, c4 = (tid & 3) * 16;
#pragma unroll
    for (int jj = 0; jj < 4; ++jj) {
        float4 v = *(const float4*)(src + (size_t)(kb + r) * N + nb + c4 + jj * 4);
        u16x4 w = { f2bf(v.x), f2bf(v.y), f2bf(v.z), f2bf(v.w) };
        *(u16x4*)(&T[r][c4 + jj * 4]) = w;
    }
    __syncthreads();
#pragma unroll
    for (int jj = 0; jj < 4; ++jj) {
        int c = c4 + jj * 4;
        u16x4 w = { T[c][r], T[c + 1][r], T[c + 2][r], T[c + 3][r] };
        *(u16x4*)(dst + (size_t)(nb + r) * 512 + kb + c) = w;
    }
}

// ---------- shared GEMM body (r12-validated): D = A[M,512] x Bt[N,512]^T ----------
// f32 operand converted to bf16 during LDS staging when AF32/BF32.
// D: lane (q,l16) reg r -> Mrow = q*4+r (consecutive), Ncol = l16.
// MODE 0 (out): A=Wu_t (cho as M), B=at -> out[t][512] float4 + bias.
// MODE 1 (qk):  A=Wqk_t (ch as M), B=cond f32 -> Qh[b,h,t,64]*CEXP / Kh, u16x4.
// MODE 2 (v):   A=x f32 (tok as M), B=Wv_t -> Vb[b,h,kt,64d,64k], u16x4 along k64.
template <typename OutT, int MODE, bool AF32, bool BF32, int TM, int TN>
__device__ __forceinline__ void gemm_body(int m0, int n0,
                                          const void* __restrict__ Ap, const void* __restrict__ Bp,
                                          const float* __restrict__ bias, OutT* __restrict__ C,
                                          OutT* __restrict__ C2, u16* As, u16* Bs) {
    const int K = 512;
    constexpr int MI = TM / 32, NJ = TN / 32;
    constexpr int NAF = TM / 32, NAB = TM / 64;
    constexpr int NBF = TN / 32, NBB = TN / 64;
    int tid = threadIdx.x;
    int wave = tid >> 6, lane = tid & 63, l16 = lane & 15, q = lane >> 4;
    int mo = (wave & 1) * (TM / 2), no = (wave >> 1) * (TN / 2);

    f32x4 acc[MI][NJ];
#pragma unroll
    for (int i = 0; i < MI; ++i)
#pragma unroll
        for (int j = 0; j < NJ; ++j) acc[i][j] = (f32x4){0.f, 0.f, 0.f, 0.f};

    const float* Af = (const float*)Ap; const u16* Ab = (const u16*)Ap;
    const float* Bf = (const float*)Bp; const u16* Bb = (const u16*)Bp;

    const float* apf[NAF > 0 ? NAF : 1]; const u16* apb[NAB > 0 ? NAB : 1];
    const float* bpf[NBF > 0 ? NBF : 1]; const u16* bpb[NBB > 0 ? NBB : 1];
    float4 raf[NAF > 0 ? NAF : 1], rbf[NBF > 0 ? NBF : 1];
    short8 rab[NAB > 0 ? NAB : 1], rbb[NBB > 0 ? NBB : 1];

    if constexpr (AF32) {
#pragma unroll
        for (int jj = 0; jj < NAF; ++jj) {
            int id = tid + 256 * jj;
            apf[jj] = Af + (size_t)(m0 + (id >> 3)) * K + (id & 7) * 4;
            raf[jj] = *(const float4*)(apf[jj]);
        }
    } else {
#pragma unroll
        for (int jj = 0; jj < NAB; ++jj) {
            int id = tid + 256 * jj;
            apb[jj] = Ab + (size_t)(m0 + (id >> 2)) * K + (id & 3) * 8;
            rab[jj] = *(const short8*)(apb[jj]);
        }
    }
    if constexpr (BF32) {
#pragma unroll
        for (int jj = 0; jj < NBF; ++jj) {
            int id = tid + 256 * jj;
            bpf[jj] = Bf + (size_t)(n0 + (id >> 3)) * K + (id & 7) * 4;
            rbf[jj] = *(const float4*)(bpf[jj]);
        }
    } else {
#pragma unroll
        for (int jj = 0; jj < NBB; ++jj) {
            int id = tid + 256 * jj;
            bpb[jj] = Bb + (size_t)(n0 + (id >> 2)) * K + (id & 3) * 8;
            rbb[jj] = *(const short8*)(bpb[jj]);
        }
    }

#pragma unroll 1
    for (int k0 = 0; k0 < K; k0 += 32) {
        __syncthreads();
        if constexpr (AF32) {
#pragma unroll
            for (int jj = 0; jj < NAF; ++jj) {
                int id = tid + 256 * jj;
                u16x4 w = { f2bf(raf[jj].x), f2bf(raf[jj].y), f2bf(raf[jj].z), f2bf(raf[jj].w) };
                *(u16x4*)(&As[(id >> 3) * 72 + (id & 7) * 4]) = w;
            }
        } else {
#pragma unroll
            for (int jj = 0; jj < NAB; ++jj) {
                int id = tid + 256 * jj;
                *(short8*)(&As[(id >> 2) * 72 + (id & 3) * 8]) = rab[jj];
            }
        }
        if constexpr (BF32) {
#pragma unroll
            for (int jj = 0; jj < NBF; ++jj) {
                int id = tid + 256 * jj;
                u16x4 w = { f2bf(rbf[jj].x), f2bf(rbf[jj].y), f2bf(rbf[jj].z), f2bf(rbf[jj].w) };
                *(u16x4*)(&Bs[(id >> 3) * 72 + (id & 7) * 4]) = w;
            }
        } else {
#pragma unroll
            for (int jj = 0; jj < NBB; ++jj) {
                int id = tid + 256 * jj;
                *(short8*)(&Bs[(id >> 2) * 72 + (id & 3) * 8]) = rbb[jj];
            }
        }
        __syncthreads();

        int kadv = (k0 + 32 < K) ? 32 : 0;
        if constexpr (AF32) {
#pragma unroll
            for (int jj = 0; jj < NAF; ++jj) { apf[jj] += kadv; raf[jj] = *(const float4*)(apf[jj]); }
        } else {
#pragma unroll
            for (int jj = 0; jj < NAB; ++jj) { apb[jj] += kadv; rab[jj] = *(const short8*)(apb[jj]); }
        }
        if constexpr (BF32) {
#pragma unroll
            for (int jj = 0; jj < NBF; ++jj) { bpf[jj] += kadv; rbf[jj] = *(const float4*)(bpf[jj]); }
        } else {
#pragma unroll
            for (int jj = 0; jj < NBB; ++jj) { bpb[jj] += kadv; rbb[jj] = *(const short8*)(bpb[jj]); }
        }
        __builtin_amdgcn_sched_barrier(0);

        short8 af[MI], bf[NJ];
#pragma unroll
        for (int i = 0; i < MI; ++i) af[i] = *(const short8*)(&As[(mo + i * 16 + l16) * 72 + q * 8]);
#pragma unroll
        for (int j = 0; j < NJ; ++j) bf[j] = *(const short8*)(&Bs[(no + j * 16 + l16) * 72 + q * 8]);
#pragma unroll
        for (int i = 0; i < MI; ++i)
#pragma unroll
            for (int j = 0; j < NJ; ++j) acc[i][j] = mfma16(af[i], bf[j], acc[i][j]);
    }

    // epilogue: Mrow = m0+mo+i*16+q*4+r (r consecutive), Ncol = n0+no+j*16+l16
#pragma unroll
    for (int i = 0; i < MI; ++i) {
        int mb = m0 + mo + i * 16 + q * 4;
#pragma unroll
        for (int j = 0; j < NJ; ++j) {
            int nc = n0 + no + j * 16 + l16;
            if constexpr (MODE == 0) {
                float4 bb = *(const float4*)(bias + mb);
                float4 w = { acc[i][j][0] + bb.x, acc[i][j][1] + bb.y,
                             acc[i][j][2] + bb.z, acc[i][j][3] + bb.w };
                *(float4*)(&C[(size_t)nc * 512 + mb]) = w;
            } else if constexpr (MODE == 1) {
                int b = nc >> 12, t = nc & 4095;
                int h = (mb & 511) >> 6, d = mb & 63;
                size_t addr = ((size_t)((b * 8 + h) * 4096 + t)) * 64 + d;
                if (mb < 512) {
                    u16x4 w = { f2bf(acc[i][j][0] * CEXP), f2bf(acc[i][j][1] * CEXP),
                                f2bf(acc[i][j][2] * CEXP), f2bf(acc[i][j][3] * CEXP) };
                    *(u16x4*)(&C[addr]) = w;
                } else {
                    u16x4 w = { f2bf(acc[i][j][0]), f2bf(acc[i][j][1]),
                                f2bf(acc[i][j][2]), f2bf(acc[i][j][3]) };
                    *(u16x4*)(&C2[addr]) = w;
                }
            } else {                                           // v: M=token, N=ch
                int b = mb >> 12, t = mb & 4095;
                int kt = t >> 6, k64 = t & 63;
                int h = nc >> 6, d = nc & 63;
                size_t addr = ((((size_t)(b * 8 + h) * 64 + kt) * 64 + d) << 6) + k64;
                u16x4 w = { f2bf(acc[i][j][0]), f2bf(acc[i][j][1]),
                            f2bf(acc[i][j][2]), f2bf(acc[i][j][3]) };
                *(u16x4*)(&C[addr]) = w;
            }
        }
    }
}

// ---------- fused qk-proj + v-proj (independent -> one launch, they overlap) ----------
// bid<1024: qk. A=Wqk_t (1024ch, TM=128), B=cond f32 (8192tok, TN=64).
//   bx-major order: the 8 blocks sharing a cond stripe are == mod 8 -> same XCD L2.
// bid>=1024: v. A=x f32 (8192tok, TM=128), B=Wv_t (512ch, TN=64).
//   by-major order: the 8 blocks sharing an x stripe are == mod 8 -> same XCD L2.
__global__ __launch_bounds__(256) void k_qkv(const u16* __restrict__ Wqk_t, const float* __restrict__ cond,
                                             const float* __restrict__ x, const u16* __restrict__ Wv_t,
                                             u16* __restrict__ Qh, u16* __restrict__ Kh,
                                             u16* __restrict__ Vb) {
    __shared__ __align__(16) u16 smem[(128 + 64) * 72];
    u16* As = smem;
    u16* Bs = smem + 128 * 72;
    int bid = blockIdx.x;
    if (bid < 1024) {
        int bx = bid >> 7, by = bid & 127;                 // 8 x 128
        gemm_body<u16, 1, false, true, 128, 64>(bx * 128, by * 64, Wqk_t, cond, nullptr, Qh, Kh, As, Bs);
    } else {
        int bid2 = bid - 1024;                             // 512 blocks
        int by = bid2 >> 6, bx = bid2 & 63;                // 8 x 64
        gemm_body<u16, 2, true, false, 128, 64>(bx * 128, by * 64, x, Wv_t, nullptr, Vb, nullptr, As, Bs);
    }
}

// ---------- out proj ----------
__global__ __launch_bounds__(256) void k_out(const u16* __restrict__ Wu_t, const u16* __restrict__ at,
                                             const float* __restrict__ bu, float* __restrict__ out) {
    __shared__ __align__(16) u16 smem[(64 + 64) * 72];
    int bid = blockIdx.x;
    int bx = bid >> 7, by = bid & 127;                     // 8 x 128
    gemm_body<float, 0, false, false, 64, 64>(bx * 64, by * 64, Wu_t, at, bu, out, nullptr,
                                              smem, smem + 64 * 72);
}

// ---------- flash: 8-wave in-block split-K (UNCHANGED from r14/r15: validated ~95us) ----------
__global__ __launch_bounds__(512) void k_flash(const u16* __restrict__ Qh, const u16* __restrict__ Kh,
                                               const u16* __restrict__ Vb, u16* __restrict__ o) {
    int bid = blockIdx.x;
    int h = bid & 7, qt = (bid >> 3) & 31, b = bid >> 8;
    int tid = threadIdx.x;
    int wave = tid >> 6, lane = tid & 63, l16 = lane & 15, q = lane >> 4;
    int ks = wave >> 2, w4 = wave & 3;
    int t256 = tid & 255;

    __shared__ __align__(16) u16 smem[2 * (64 * 80 + 64 * 72)];   // 38912 B
    u16* Kt = smem + ks * (64 * 80 + 64 * 72);
    u16* Vt = Kt + 64 * 80;

    int head = b * 8 + h;
    short8 qf[2][2];
#pragma unroll
    for (int g = 0; g < 2; ++g) {
        const u16* qp = Qh + ((size_t)head * 4096 + qt * 128 + g * 64 + w4 * 16 + l16) * 64 + q * 8;
        qf[g][0] = *(const short8*)(qp);
        qf[g][1] = *(const short8*)(qp + 32);
    }

    const u16* kb = Kh + (size_t)head * 4096 * 64;
    const u16* vb = Vb + (size_t)head * 4096 * 64;

    int r0 = t256 >> 3, g0 = t256 & 7;
    u16* kw0 = &Kt[r0 * 80 + g0 * 8];
    u16* kw1 = &Kt[(r0 + 32) * 80 + g0 * 8];
    u16* vw0 = &Vt[r0 * 72 + g0 * 8];
    u16* vw1 = &Vt[(r0 + 32) * 72 + g0 * 8];

    f32x4 oacc[2][4];
#pragma unroll
    for (int g = 0; g < 2; ++g)
#pragma unroll
        for (int c = 0; c < 4; ++c) oacc[g][c] = (f32x4){0.f, 0.f, 0.f, 0.f};
    f32x4 lacc[2];
    lacc[0] = (f32x4){0.f, 0.f, 0.f, 0.f};
    lacc[1] = (f32x4){0.f, 0.f, 0.f, 0.f};
    const short8 ones = { 0x3F80, 0x3F80, 0x3F80, 0x3F80, 0x3F80, 0x3F80, 0x3F80, 0x3F80 };
    int pi0 = (l16 >> 2) * 8 + (l16 & 3);

    size_t off0 = (size_t)(ks * 32 + (qt & 31)) * 4096;
    short8 rk0 = *(const short8*)(kb + off0 + t256 * 8);
    short8 rk1 = *(const short8*)(kb + off0 + t256 * 8 + 2048);
    short8 rv0 = *(const short8*)(vb + off0 + t256 * 8);
    short8 rv1 = *(const short8*)(vb + off0 + t256 * 8 + 2048);

#pragma unroll 1
    for (int it = 0; it < 32; ++it) {
        __syncthreads();
        *(short8*)kw0 = rk0;
        *(short8*)kw1 = rk1;
        *(short8*)vw0 = rv0;
        *(short8*)vw1 = rv1;
        __syncthreads();

        size_t offn = (size_t)(ks * 32 + ((qt + it + 1) & 31)) * 4096;
        rk0 = *(const short8*)(kb + offn + t256 * 8);
        rk1 = *(const short8*)(kb + offn + t256 * 8 + 2048);
        rv0 = *(const short8*)(vb + offn + t256 * 8);
        rv1 = *(const short8*)(vb + offn + t256 * 8 + 2048);
        __builtin_amdgcn_sched_barrier(0);

#pragma unroll
        for (int kk = 0; kk < 2; ++kk) {
            const u16* ka = &Kt[(kk * 32 + pi0) * 80 + q * 8];
            short8 A00 = *(const short8*)(ka);
            short8 A01 = *(const short8*)(ka + 32);
            short8 A10 = *(const short8*)(ka + 4 * 80);
            short8 A11 = *(const short8*)(ka + 4 * 80 + 32);
            short8 vfc[4];
#pragma unroll
            for (int c = 0; c < 4; ++c)
                vfc[c] = *(const short8*)(&Vt[(c * 16 + l16) * 72 + kk * 32 + q * 8]);

#pragma unroll
            for (int g = 0; g < 2; ++g) {
                f32x4 s0 = (f32x4){0.f, 0.f, 0.f, 0.f};
                f32x4 s1 = (f32x4){0.f, 0.f, 0.f, 0.f};
                s0 = mfma16(A00, qf[g][0], s0); s0 = mfma16(A01, qf[g][1], s0);
                s1 = mfma16(A10, qf[g][0], s1); s1 = mfma16(A11, qf[g][1], s1);

                uint4 pd;
                pd.x = __builtin_amdgcn_perm(rbits(__builtin_amdgcn_exp2f(s0[1])),
                                             rbits(__builtin_amdgcn_exp2f(s0[0])), 0x07060302u);
                pd.y = __builtin_amdgcn_perm(rbits(__builtin_amdgcn_exp2f(s0[3])),
                                             rbits(__builtin_amdgcn_exp2f(s0[2])), 0x07060302u);
                pd.z = __builtin_amdgcn_perm(rbits(__builtin_amdgcn_exp2f(s1[1])),
                                             rbits(__builtin_amdgcn_exp2f(s1[0])), 0x07060302u);
                pd.w = __builtin_amdgcn_perm(rbits(__builtin_amdgcn_exp2f(s1[3])),
                                             rbits(__builtin_amdgcn_exp2f(s1[2])), 0x07060302u);
                short8 pf;
                __builtin_memcpy(&pf, &pd, 16);

                lacc[g] = mfma16(ones, pf, lacc[g]);
#pragma unroll
                for (int c = 0; c < 4; ++c)
                    oacc[g][c] = mfma16(vfc[c], pf, oacc[g][c]);
            }
        }
    }

    __syncthreads();
    float* red = (float*)smem;
    if (ks == 1) {
        float* rp = red + ((w4 * 64 + lane) * 37);
#pragma unroll
        for (int g = 0; g < 2; ++g)
#pragma unroll
            for (int c = 0; c < 4; ++c)
#pragma unroll
                for (int r = 0; r < 4; ++r) rp[g * 16 + c * 4 + r] = oacc[g][c][r];
        rp[32] = lacc[0][0];
        rp[33] = lacc[1][0];
    }
    __syncthreads();
    if (ks == 0) {
        const float* rp = red + ((w4 * 64 + lane) * 37);
#pragma unroll
        for (int g = 0; g < 2; ++g) {
#pragma unroll
            for (int c = 0; c < 4; ++c)
#pragma unroll
                for (int r = 0; r < 4; ++r) oacc[g][c][r] += rp[g * 16 + c * 4 + r];
            float inv = 1.f / (lacc[g][0] + rp[32 + g]);
            u16* ob = o + (size_t)(b * T_SZ + qt * 128 + g * 64 + w4 * 16 + l16) * 512 + h * 64 + q * 4;
#pragma unroll
            for (int c = 0; c < 4; ++c) {
                u16x4 w = { f2bf(oacc[g][c][0] * inv), f2bf(oacc[g][c][1] * inv),
                            f2bf(oacc[g][c][2] * inv), f2bf(oacc[g][c][3] * inv) };
                *(u16x4*)(ob + c * 16) = w;
            }
        }
    }
}

extern "C" void kernel_launch(void* const* d_in, const int* in_sizes, int n_in,
                              void* d_out, int out_size, void* d_ws, size_t ws_size,
                              hipStream_t stream) {
    const float* x    = (const float*)d_in[0];   // [2,4096,512] f32
    const float* cond = (const float*)d_in[1];   // [2,4096,512] f32
    const float* Wqk  = (const float*)d_in[2];   // [512,1024]   f32
    const float* Wv   = (const float*)d_in[3];   // [512,512]    f32
    const float* Wu   = (const float*)d_in[4];   // [512,512]    f32
    const float* bu   = (const float*)d_in[5];   // [512]        f32
    float* out = (float*)d_out;                  // [2,4096,512] f32

    const size_t MT = (size_t)B_SZ * T_SZ;       // 8192
    u16* qh_ws = (u16*)d_ws;                     // [16 heads,4096,64]  8 MB (Q pre-scaled)
    u16* kh_ws = qh_ws + MT * 512;               // [16 heads,4096,64]  8 MB
    u16* vb_ws = kh_ws + MT * 512;               // [16,64kt,64d,64k]   8 MB
    u16* at_ws = vb_ws + MT * 512;               // [8192,512]          8 MB
    u16* Wqk_t = at_ws + MT * 512;               // [1024,512]          1 MB
    u16* Wv_t  = Wqk_t + (size_t)1024 * 512;     // [512,512]         0.5 MB
    u16* Wu_t  = Wv_t + (size_t)512 * 512;       // [512,512]         0.5 MB

    k_prep<<<256, 256, 0, stream>>>(Wqk, Wv, Wu, Wqk_t, Wv_t, Wu_t);
    k_qkv<<<1536, 256, 0, stream>>>(Wqk_t, cond, x, Wv_t, qh_ws, kh_ws, vb_ws);
    k_flash<<<512, 512, 0, stream>>>(qh_ws, kh_ws, vb_ws, at_ws);
    k_out<<<1024, 256, 0, stream>>>(Wu_t, at_ws, bu, out);
}